// Round 1
// baseline (919.055 us; speedup 1.0000x reference)
//
#include <hip/hip_runtime.h>
#include <hip/hip_bf16.h>

#define B 64
#define T_ENC 4096
#define H_ENC 512
#define H_DEC 512
#define ATTN 256

#define BM 64
#define BK 32
#define TC 128

typedef __attribute__((ext_vector_type(8))) short bf16x8;
typedef __attribute__((ext_vector_type(4))) float f32x4;

__device__ __forceinline__ unsigned short f2bf(float f) {
    unsigned int u = __float_as_uint(f);
    unsigned int rounding = 0x7fffu + ((u >> 16) & 1u);
    return (unsigned short)((u + rounding) >> 16);
}

__device__ __forceinline__ float fast_tanh(float x) {
    float ax = fabsf(x);
    float e = __expf(2.0f * fminf(ax, 15.0f));
    float t = 1.0f - 2.0f / (e + 1.0f);
    return copysignf(t, x);
}

// ---------------------------------------------------------------------------
// Kernel 1: dec_proj[b,a] = dot(decoder_state[b,:], W_dec[a,:])
// ---------------------------------------------------------------------------
__global__ void decproj_kernel(const float* __restrict__ dec,
                               const float* __restrict__ Wdec,
                               float* __restrict__ dproj) {
    __shared__ float sdec[H_DEC];
    int b = blockIdx.x;
    int tid = threadIdx.x;
    sdec[tid]       = dec[b * H_DEC + tid];
    sdec[tid + 256] = dec[b * H_DEC + tid + 256];
    __syncthreads();
    const float* wrow = Wdec + (size_t)tid * H_DEC;
    float acc = 0.0f;
#pragma unroll 4
    for (int k = 0; k < H_DEC; k += 4) {
        float4 w4 = *(const float4*)(wrow + k);
        acc += w4.x * sdec[k] + w4.y * sdec[k + 1] + w4.z * sdec[k + 2] + w4.w * sdec[k + 3];
    }
    dproj[b * ATTN + tid] = acc;
}

// ---------------------------------------------------------------------------
// Kernel 2: scores[b*T+t] = sum_a tanh(enc_proj + dec_proj) * v[a]
// Block: 256 threads (4 waves). Tile: BM=64 rows x ATTN=256 cols x BK=32.
// Wave w covers cols [w*64, w*64+64) of all 64 rows.
// ---------------------------------------------------------------------------
__global__ __launch_bounds__(256) void scores_kernel(
    const float* __restrict__ enc,    // (B*T, 512) row-major
    const float* __restrict__ Wenc,   // (256, 512) row-major
    const float* __restrict__ dproj,  // (B, 256)
    const float* __restrict__ v,      // (256)
    float* __restrict__ scores)       // (B*T)
{
    __shared__ unsigned short Abuf[BM * BK];    // 4 KB bf16
    __shared__ unsigned short Bbuf[ATTN * BK];  // 16 KB bf16
    __shared__ float sPart[BM * 4];             // per-row per-wave partials

    const int tid  = threadIdx.x;
    const int wave = tid >> 6;
    const int lane = tid & 63;
    const int quad = lane >> 4;
    const int l16  = lane & 15;
    const int m0   = blockIdx.x * BM;      // global row base (bt index)
    const int b    = m0 >> 12;             // T_ENC = 4096, BM divides it

    f32x4 acc[4][4];
#pragma unroll
    for (int mi = 0; mi < 4; ++mi)
#pragma unroll
        for (int ni = 0; ni < 4; ++ni) {
            f32x4 z = {0.0f, 0.0f, 0.0f, 0.0f};
            acc[mi][ni] = z;
        }

    for (int k0 = 0; k0 < H_ENC; k0 += BK) {
        // ---- stage A tile: 64 rows x 32 cols of enc, converted to bf16 ----
#pragma unroll
        for (int rep = 0; rep < 2; ++rep) {
            int idx = rep * 1024 + tid * 4;
            int r = idx >> 5, c = idx & 31;
            float4 x = *(const float4*)(enc + (size_t)(m0 + r) * H_ENC + k0 + c);
            ushort4 u;
            u.x = f2bf(x.x); u.y = f2bf(x.y); u.z = f2bf(x.z); u.w = f2bf(x.w);
            *(ushort4*)(&Abuf[r * BK + c]) = u;
        }
        // ---- stage B tile: 256 rows (a) x 32 cols (k) of W_enc ----
#pragma unroll
        for (int rep = 0; rep < 8; ++rep) {
            int idx = rep * 1024 + tid * 4;
            int r = idx >> 5, c = idx & 31;
            float4 x = *(const float4*)(Wenc + (size_t)r * H_ENC + k0 + c);
            ushort4 u;
            u.x = f2bf(x.x); u.y = f2bf(x.y); u.z = f2bf(x.z); u.w = f2bf(x.w);
            *(ushort4*)(&Bbuf[r * BK + c]) = u;
        }
        __syncthreads();

        bf16x8 afrag[4], bfrag[4];
#pragma unroll
        for (int mi = 0; mi < 4; ++mi)
            afrag[mi] = *(const bf16x8*)(&Abuf[(mi * 16 + l16) * BK + quad * 8]);
#pragma unroll
        for (int ni = 0; ni < 4; ++ni)
            bfrag[ni] = *(const bf16x8*)(&Bbuf[(wave * 64 + ni * 16 + l16) * BK + quad * 8]);

#pragma unroll
        for (int mi = 0; mi < 4; ++mi)
#pragma unroll
            for (int ni = 0; ni < 4; ++ni)
                acc[mi][ni] = __builtin_amdgcn_mfma_f32_16x16x32_bf16(
                    afrag[mi], bfrag[ni], acc[mi][ni], 0, 0, 0);
        __syncthreads();
    }

    // ---- epilogue: tanh(c + dec_proj) * v, reduce over a ----
    float decp[4], vv[4];
#pragma unroll
    for (int ni = 0; ni < 4; ++ni) {
        int a = wave * 64 + ni * 16 + l16;
        decp[ni] = dproj[b * ATTN + a];
        vv[ni]   = v[a];
    }
#pragma unroll
    for (int mi = 0; mi < 4; ++mi) {
#pragma unroll
        for (int r = 0; r < 4; ++r) {
            float sum = 0.0f;
#pragma unroll
            for (int ni = 0; ni < 4; ++ni) {
                float x = acc[mi][ni][r] + decp[ni];
                sum += fast_tanh(x) * vv[ni];
            }
            // reduce across the 16 lanes of this quad (distinct cols)
            sum += __shfl_xor(sum, 1);
            sum += __shfl_xor(sum, 2);
            sum += __shfl_xor(sum, 4);
            sum += __shfl_xor(sum, 8);
            if (l16 == 0) {
                int m = mi * 16 + quad * 4 + r;     // local row
                sPart[m * 4 + wave] = sum;
            }
        }
    }
    __syncthreads();
    if (tid < BM) {
        float s = sPart[tid * 4 + 0] + sPart[tid * 4 + 1] +
                  sPart[tid * 4 + 2] + sPart[tid * 4 + 3];
        scores[m0 + tid] = s;
    }
}

// ---------------------------------------------------------------------------
// Kernel 3: softmax over T per batch; writes attn weights; zeros context region
// ---------------------------------------------------------------------------
__global__ void softmax_kernel(const float* __restrict__ scores,
                               float* __restrict__ out) {
    __shared__ float redm[4], reds[4];
    int b = blockIdx.x, tid = threadIdx.x;
    int wave = tid >> 6, lane = tid & 63;
    const float* sb = scores + (size_t)b * T_ENC;
    float s[16];
    float m = -1e30f;
#pragma unroll
    for (int i = 0; i < 16; ++i) {
        s[i] = sb[i * 256 + tid];
        m = fmaxf(m, s[i]);
    }
#pragma unroll
    for (int o = 1; o < 64; o <<= 1) m = fmaxf(m, __shfl_xor(m, o));
    if (lane == 0) redm[wave] = m;
    __syncthreads();
    m = fmaxf(fmaxf(redm[0], redm[1]), fmaxf(redm[2], redm[3]));
    float sum = 0.0f;
#pragma unroll
    for (int i = 0; i < 16; ++i) {
        s[i] = __expf(s[i] - m);
        sum += s[i];
    }
#pragma unroll
    for (int o = 1; o < 64; o <<= 1) sum += __shfl_xor(sum, o);
    if (lane == 0) reds[wave] = sum;
    __syncthreads();
    float inv = 1.0f / (reds[0] + reds[1] + reds[2] + reds[3]);
    float* attn = out + B * H_ENC + (size_t)b * T_ENC;
#pragma unroll
    for (int i = 0; i < 16; ++i) attn[i * 256 + tid] = s[i] * inv;
    // zero the context accumulation region (d_out is poisoned 0xAA)
    out[b * H_ENC + tid] = 0.0f;
    out[b * H_ENC + 256 + tid] = 0.0f;
}

// ---------------------------------------------------------------------------
// Kernel 4: context[b,e] += sum_t attn[b,t] * enc[b,t,e]  (atomic partials)
// ---------------------------------------------------------------------------
__global__ void context_kernel(const float* __restrict__ enc,
                               const float* __restrict__ attnw,
                               float* __restrict__ ctx) {
    __shared__ float w[TC];
    int b = blockIdx.x;
    int t0 = blockIdx.y * TC;
    int tid = threadIdx.x;
    if (tid < TC) w[tid] = attnw[(size_t)b * T_ENC + t0 + tid];
    __syncthreads();
    float2 acc = {0.0f, 0.0f};
    const float* base = enc + ((size_t)b * T_ENC + t0) * H_ENC + tid * 2;
#pragma unroll 4
    for (int t = 0; t < TC; ++t) {
        float2 x = *(const float2*)(base + (size_t)t * H_ENC);
        acc.x += w[t] * x.x;
        acc.y += w[t] * x.y;
    }
    atomicAdd(&ctx[b * H_ENC + tid * 2], acc.x);
    atomicAdd(&ctx[b * H_ENC + tid * 2 + 1], acc.y);
}

extern "C" void kernel_launch(void* const* d_in, const int* in_sizes, int n_in,
                              void* d_out, int out_size, void* d_ws, size_t ws_size,
                              hipStream_t stream) {
    const float* dec  = (const float*)d_in[0];
    const float* enc  = (const float*)d_in[1];
    const float* Wenc = (const float*)d_in[2];
    const float* Wdec = (const float*)d_in[3];
    const float* v    = (const float*)d_in[4];
    float* out = (float*)d_out;
    float* ws  = (float*)d_ws;

    float* scores = ws;                      // B*T_ENC floats (1 MB)
    float* dproj  = ws + (size_t)B * T_ENC;  // B*ATTN floats

    hipLaunchKernelGGL(decproj_kernel, dim3(B), dim3(256), 0, stream, dec, Wdec, dproj);
    hipLaunchKernelGGL(scores_kernel, dim3((B * T_ENC) / BM), dim3(256), 0, stream,
                       enc, Wenc, dproj, v, scores);
    hipLaunchKernelGGL(softmax_kernel, dim3(B), dim3(256), 0, stream, scores, out);
    hipLaunchKernelGGL(context_kernel, dim3(B, T_ENC / TC), dim3(256), 0, stream,
                       enc, out + B * H_ENC, out);
}

// Round 2
// 896.108 us; speedup vs baseline: 1.0256x; 1.0256x over previous
//
#include <hip/hip_runtime.h>
#include <hip/hip_bf16.h>

#define B 64
#define T_ENC 4096
#define H_ENC 512
#define H_DEC 512
#define ATTN 256

#define BM 64
#define BK 32
#define LDA 40   // padded LDS row stride (shorts): 80 B = 16B-aligned, bank-rotation 20 -> <=2-way
#define TC 256

typedef __attribute__((ext_vector_type(8))) short bf16x8;
typedef __attribute__((ext_vector_type(4))) float f32x4;

__device__ __forceinline__ unsigned short f2bf(float f) {
    unsigned int u = __float_as_uint(f);
    unsigned int rounding = 0x7fffu + ((u >> 16) & 1u);
    return (unsigned short)((u + rounding) >> 16);
}

__device__ __forceinline__ float fast_tanh(float x) {
    float ax = fabsf(x);
    float e = __expf(2.0f * fminf(ax, 15.0f));
    float t = 1.0f - 2.0f / (e + 1.0f);
    return copysignf(t, x);
}

// ---------------------------------------------------------------------------
// Kernel 0: one-time W_enc fp32 -> bf16 (256 KB, L2-resident afterwards)
// ---------------------------------------------------------------------------
__global__ void convw_kernel(const float* __restrict__ W,
                             unsigned short* __restrict__ out) {
    int i = (blockIdx.x * 256 + threadIdx.x) * 4;
    float4 x = *(const float4*)(W + i);
    ushort4 u;
    u.x = f2bf(x.x); u.y = f2bf(x.y); u.z = f2bf(x.z); u.w = f2bf(x.w);
    *(ushort4*)(out + i) = u;
}

// ---------------------------------------------------------------------------
// Kernel 1: dec_proj[b,a] = dot(decoder_state[b,:], W_dec[a,:])
// ---------------------------------------------------------------------------
__global__ void decproj_kernel(const float* __restrict__ dec,
                               const float* __restrict__ Wdec,
                               float* __restrict__ dproj) {
    __shared__ float sdec[H_DEC];
    int b = blockIdx.x;
    int tid = threadIdx.x;
    sdec[tid]       = dec[b * H_DEC + tid];
    sdec[tid + 256] = dec[b * H_DEC + tid + 256];
    __syncthreads();
    const float* wrow = Wdec + (size_t)tid * H_DEC;
    float acc = 0.0f;
#pragma unroll 4
    for (int k = 0; k < H_DEC; k += 4) {
        float4 w4 = *(const float4*)(wrow + k);
        acc += w4.x * sdec[k] + w4.y * sdec[k + 1] + w4.z * sdec[k + 2] + w4.w * sdec[k + 3];
    }
    dproj[b * ATTN + tid] = acc;
}

// ---------------------------------------------------------------------------
// Kernel 2: scores[b*T+t] = sum_a tanh(enc_proj + dec_proj) * v[a]
// Block: 256 threads (4 waves). Tile: BM=64 rows x ATTN=256 cols x BK=32.
// Wave w covers cols [w*64, w*64+64). W_enc arrives pre-converted bf16.
// ---------------------------------------------------------------------------
__global__ __launch_bounds__(256) void scores_kernel(
    const float* __restrict__ enc,             // (B*T, 512) fp32
    const unsigned short* __restrict__ wencb,  // (256, 512) bf16
    const float* __restrict__ dproj,           // (B, 256)
    const float* __restrict__ v,               // (256)
    float* __restrict__ scores)                // (B*T)
{
    __shared__ unsigned short Abuf[BM * LDA];    // 5 KB
    __shared__ unsigned short Bbuf[ATTN * LDA];  // 20 KB
    __shared__ float sPart[BM * 4];

    const int tid  = threadIdx.x;
    const int wave = tid >> 6;
    const int lane = tid & 63;
    const int quad = lane >> 4;
    const int l16  = lane & 15;
    const int m0   = blockIdx.x * BM;
    const int b    = m0 >> 12;

    f32x4 acc[4][4];
#pragma unroll
    for (int mi = 0; mi < 4; ++mi)
#pragma unroll
        for (int ni = 0; ni < 4; ++ni) {
            f32x4 z = {0.0f, 0.0f, 0.0f, 0.0f};
            acc[mi][ni] = z;
        }

    for (int k0 = 0; k0 < H_ENC; k0 += BK) {
        // ---- stage A: 64 rows x 32 cols of enc, fp32 -> bf16 ----
#pragma unroll
        for (int rep = 0; rep < 2; ++rep) {
            int idx = rep * 1024 + tid * 4;          // element index in 64x32 tile
            int r = idx >> 5, c = idx & 31;
            float4 x = *(const float4*)(enc + (size_t)(m0 + r) * H_ENC + k0 + c);
            ushort4 u;
            u.x = f2bf(x.x); u.y = f2bf(x.y); u.z = f2bf(x.z); u.w = f2bf(x.w);
            *(ushort4*)(&Abuf[r * LDA + c]) = u;
        }
        // ---- stage B: 256 rows x 32 cols of bf16 W_enc, 16B chunks ----
#pragma unroll
        for (int rep = 0; rep < 4; ++rep) {
            int chunk = rep * 256 + tid;             // 1024 chunks of 8 elems
            int r = chunk >> 2, off = (chunk & 3) * 8;
            bf16x8 x = *(const bf16x8*)(wencb + (size_t)r * H_ENC + k0 + off);
            *(bf16x8*)(&Bbuf[r * LDA + off]) = x;
        }
        __syncthreads();

        bf16x8 afrag[4], bfrag[4];
#pragma unroll
        for (int mi = 0; mi < 4; ++mi)
            afrag[mi] = *(const bf16x8*)(&Abuf[(mi * 16 + l16) * LDA + quad * 8]);
#pragma unroll
        for (int ni = 0; ni < 4; ++ni)
            bfrag[ni] = *(const bf16x8*)(&Bbuf[(wave * 64 + ni * 16 + l16) * LDA + quad * 8]);

#pragma unroll
        for (int mi = 0; mi < 4; ++mi)
#pragma unroll
            for (int ni = 0; ni < 4; ++ni)
                acc[mi][ni] = __builtin_amdgcn_mfma_f32_16x16x32_bf16(
                    afrag[mi], bfrag[ni], acc[mi][ni], 0, 0, 0);
        __syncthreads();
    }

    // ---- epilogue: tanh(c + dec_proj) * v, reduce over a ----
    float decp[4], vv[4];
#pragma unroll
    for (int ni = 0; ni < 4; ++ni) {
        int a = wave * 64 + ni * 16 + l16;
        decp[ni] = dproj[b * ATTN + a];
        vv[ni]   = v[a];
    }
#pragma unroll
    for (int mi = 0; mi < 4; ++mi) {
#pragma unroll
        for (int r = 0; r < 4; ++r) {
            float sum = 0.0f;
#pragma unroll
            for (int ni = 0; ni < 4; ++ni) {
                float x = acc[mi][ni][r] + decp[ni];
                sum += fast_tanh(x) * vv[ni];
            }
            sum += __shfl_xor(sum, 1);
            sum += __shfl_xor(sum, 2);
            sum += __shfl_xor(sum, 4);
            sum += __shfl_xor(sum, 8);
            if (l16 == 0) {
                int m = mi * 16 + quad * 4 + r;
                sPart[m * 4 + wave] = sum;
            }
        }
    }
    __syncthreads();
    if (tid < BM) {
        float s = sPart[tid * 4 + 0] + sPart[tid * 4 + 1] +
                  sPart[tid * 4 + 2] + sPart[tid * 4 + 3];
        scores[m0 + tid] = s;
    }
}

// ---------------------------------------------------------------------------
// Kernel 3: softmax over T per batch; writes attn weights; zeros context region
// ---------------------------------------------------------------------------
__global__ void softmax_kernel(const float* __restrict__ scores,
                               float* __restrict__ out) {
    __shared__ float redm[4], reds[4];
    int b = blockIdx.x, tid = threadIdx.x;
    int wave = tid >> 6, lane = tid & 63;
    const float* sb = scores + (size_t)b * T_ENC;
    float s[16];
    float m = -1e30f;
#pragma unroll
    for (int i = 0; i < 16; ++i) {
        s[i] = sb[i * 256 + tid];
        m = fmaxf(m, s[i]);
    }
#pragma unroll
    for (int o = 1; o < 64; o <<= 1) m = fmaxf(m, __shfl_xor(m, o));
    if (lane == 0) redm[wave] = m;
    __syncthreads();
    m = fmaxf(fmaxf(redm[0], redm[1]), fmaxf(redm[2], redm[3]));
    float sum = 0.0f;
#pragma unroll
    for (int i = 0; i < 16; ++i) {
        s[i] = __expf(s[i] - m);
        sum += s[i];
    }
#pragma unroll
    for (int o = 1; o < 64; o <<= 1) sum += __shfl_xor(sum, o);
    if (lane == 0) reds[wave] = sum;
    __syncthreads();
    float inv = 1.0f / (reds[0] + reds[1] + reds[2] + reds[3]);
    float* attn = out + B * H_ENC + (size_t)b * T_ENC;
#pragma unroll
    for (int i = 0; i < 16; ++i) attn[i * 256 + tid] = s[i] * inv;
    out[b * H_ENC + tid] = 0.0f;
    out[b * H_ENC + 256 + tid] = 0.0f;
}

// ---------------------------------------------------------------------------
// Kernel 4: context[b,e] += sum_t attn[b,t] * enc[b,t,e]  (atomic partials)
// 256 threads: 128 threads span H_ENC with float4; 2 rows in flight.
// ---------------------------------------------------------------------------
__global__ void context_kernel(const float* __restrict__ enc,
                               const float* __restrict__ attnw,
                               float* __restrict__ ctx) {
    __shared__ float w[TC];
    int b = blockIdx.x;
    int t0 = blockIdx.y * TC;
    int tid = threadIdx.x;
    w[tid] = attnw[(size_t)b * T_ENC + t0 + tid];
    __syncthreads();
    int e  = (tid & 127) * 4;
    int tl = tid >> 7;
    const float* base = enc + ((size_t)b * T_ENC + t0 + tl) * H_ENC + e;
    float4 acc = {0.0f, 0.0f, 0.0f, 0.0f};
#pragma unroll 4
    for (int i = 0; i < TC; i += 2) {
        float4 x = *(const float4*)(base + (size_t)i * H_ENC);
        float wt = w[i + tl];
        acc.x += wt * x.x; acc.y += wt * x.y;
        acc.z += wt * x.z; acc.w += wt * x.w;
    }
    float* c = &ctx[b * H_ENC + e];
    atomicAdd(c + 0, acc.x);
    atomicAdd(c + 1, acc.y);
    atomicAdd(c + 2, acc.z);
    atomicAdd(c + 3, acc.w);
}

extern "C" void kernel_launch(void* const* d_in, const int* in_sizes, int n_in,
                              void* d_out, int out_size, void* d_ws, size_t ws_size,
                              hipStream_t stream) {
    const float* dec  = (const float*)d_in[0];
    const float* enc  = (const float*)d_in[1];
    const float* Wenc = (const float*)d_in[2];
    const float* Wdec = (const float*)d_in[3];
    const float* v    = (const float*)d_in[4];
    float* out = (float*)d_out;
    float* ws  = (float*)d_ws;

    float* scores = ws;                                    // 262144 floats
    float* dproj  = ws + (size_t)B * T_ENC;                // 16384 floats
    unsigned short* wencb = (unsigned short*)(ws + (size_t)B * T_ENC + B * ATTN);

    hipLaunchKernelGGL(convw_kernel, dim3((ATTN * H_ENC) / 1024), dim3(256), 0, stream,
                       Wenc, wencb);
    hipLaunchKernelGGL(decproj_kernel, dim3(B), dim3(256), 0, stream, dec, Wdec, dproj);
    hipLaunchKernelGGL(scores_kernel, dim3((B * T_ENC) / BM), dim3(256), 0, stream,
                       enc, wencb, dproj, v, scores);
    hipLaunchKernelGGL(softmax_kernel, dim3(B), dim3(256), 0, stream, scores, out);
    hipLaunchKernelGGL(context_kernel, dim3(B, T_ENC / TC), dim3(256), 0, stream,
                       enc, out + B * H_ENC, out);
}

// Round 3
// 875.316 us; speedup vs baseline: 1.0500x; 1.0238x over previous
//
#include <hip/hip_runtime.h>
#include <hip/hip_bf16.h>

#define B 64
#define T_ENC 4096
#define H_ENC 512
#define H_DEC 512
#define ATTN 256

#define BM 64
#define BK 32
#define LDA 40   // padded LDS row stride (shorts): 80 B, 16B-aligned, <=2-way banks

typedef __attribute__((ext_vector_type(8))) short bf16x8;
typedef __attribute__((ext_vector_type(4))) float f32x4;

__device__ __forceinline__ unsigned short f2bf(float f) {
    unsigned int u = __float_as_uint(f);
    unsigned int rounding = 0x7fffu + ((u >> 16) & 1u);
    return (unsigned short)((u + rounding) >> 16);
}

__device__ __forceinline__ float fast_tanh(float x) {
    float ax = fabsf(x);
    float e = __expf(2.0f * fminf(ax, 15.0f));
    float t = 1.0f - 2.0f / (e + 1.0f);
    return copysignf(t, x);
}

// ---------------------------------------------------------------------------
// Kernel 0: one-time W_enc fp32 -> bf16 (256 KB, L2-resident afterwards)
// ---------------------------------------------------------------------------
__global__ void convw_kernel(const float* __restrict__ W,
                             unsigned short* __restrict__ out) {
    int i = (blockIdx.x * 256 + threadIdx.x) * 4;
    float4 x = *(const float4*)(W + i);
    ushort4 u;
    u.x = f2bf(x.x); u.y = f2bf(x.y); u.z = f2bf(x.z); u.w = f2bf(x.w);
    *(ushort4*)(out + i) = u;
}

// ---------------------------------------------------------------------------
// Kernel 1: dec_proj[b,a] = dot(decoder_state[b,:], W_dec[a,:])
// ---------------------------------------------------------------------------
__global__ void decproj_kernel(const float* __restrict__ dec,
                               const float* __restrict__ Wdec,
                               float* __restrict__ dproj) {
    __shared__ float sdec[H_DEC];
    int b = blockIdx.x;
    int tid = threadIdx.x;
    sdec[tid]       = dec[b * H_DEC + tid];
    sdec[tid + 256] = dec[b * H_DEC + tid + 256];
    __syncthreads();
    const float* wrow = Wdec + (size_t)tid * H_DEC;
    float acc = 0.0f;
#pragma unroll 4
    for (int k = 0; k < H_DEC; k += 4) {
        float4 w4 = *(const float4*)(wrow + k);
        acc += w4.x * sdec[k] + w4.y * sdec[k + 1] + w4.z * sdec[k + 2] + w4.w * sdec[k + 3];
    }
    dproj[b * ATTN + tid] = acc;
}

// ---------------------------------------------------------------------------
// Kernel 2 (FUSED): per 64-row chunk of (b,t):
//   scores -> chunk-local softmax numerators p_t -> partial context
// Writes: raw scores (for exact attn later), per-chunk (m_loc, l_loc),
//         per-chunk partial context ctxp[512] (fp32, from fp32 enc re-read
//         that hits L2/L3 since the chunk was just streamed in pass 1).
// ---------------------------------------------------------------------------
__global__ __launch_bounds__(256) void fused_kernel(
    const float* __restrict__ enc,             // (B*T, 512) fp32
    const unsigned short* __restrict__ wencb,  // (256, 512) bf16
    const float* __restrict__ dproj,           // (B, 256)
    const float* __restrict__ v,               // (256)
    float* __restrict__ scores,                // (B*T)
    float* __restrict__ ctxp,                  // (nchunks, 512)
    float* __restrict__ ml)                    // (nchunks, 2)
{
    __shared__ unsigned short Abuf[BM * LDA];    // 5 KB
    __shared__ unsigned short Bbuf[ATTN * LDA];  // 20 KB
    __shared__ float sPart[BM * 4];
    __shared__ float sP[BM];                     // chunk-local softmax numerators

    const int tid  = threadIdx.x;
    const int wave = tid >> 6;
    const int lane = tid & 63;
    const int quad = lane >> 4;
    const int l16  = lane & 15;
    const int chunk = blockIdx.x;
    const int m0   = chunk * BM;
    const int b    = m0 >> 12;

    f32x4 acc[4][4];
#pragma unroll
    for (int mi = 0; mi < 4; ++mi)
#pragma unroll
        for (int ni = 0; ni < 4; ++ni) {
            f32x4 z = {0.0f, 0.0f, 0.0f, 0.0f};
            acc[mi][ni] = z;
        }

    for (int k0 = 0; k0 < H_ENC; k0 += BK) {
        // ---- stage A: 64 rows x 32 cols of enc, fp32 -> bf16 ----
#pragma unroll
        for (int rep = 0; rep < 2; ++rep) {
            int idx = rep * 1024 + tid * 4;
            int r = idx >> 5, c = idx & 31;
            float4 x = *(const float4*)(enc + (size_t)(m0 + r) * H_ENC + k0 + c);
            ushort4 u;
            u.x = f2bf(x.x); u.y = f2bf(x.y); u.z = f2bf(x.z); u.w = f2bf(x.w);
            *(ushort4*)(&Abuf[r * LDA + c]) = u;
        }
        // ---- stage B: 256 rows x 32 cols of bf16 W_enc ----
#pragma unroll
        for (int rep = 0; rep < 4; ++rep) {
            int chnk = rep * 256 + tid;
            int r = chnk >> 2, off = (chnk & 3) * 8;
            bf16x8 x = *(const bf16x8*)(wencb + (size_t)r * H_ENC + k0 + off);
            *(bf16x8*)(&Bbuf[r * LDA + off]) = x;
        }
        __syncthreads();

        bf16x8 afrag[4], bfrag[4];
#pragma unroll
        for (int mi = 0; mi < 4; ++mi)
            afrag[mi] = *(const bf16x8*)(&Abuf[(mi * 16 + l16) * LDA + quad * 8]);
#pragma unroll
        for (int ni = 0; ni < 4; ++ni)
            bfrag[ni] = *(const bf16x8*)(&Bbuf[(wave * 64 + ni * 16 + l16) * LDA + quad * 8]);

#pragma unroll
        for (int mi = 0; mi < 4; ++mi)
#pragma unroll
            for (int ni = 0; ni < 4; ++ni)
                acc[mi][ni] = __builtin_amdgcn_mfma_f32_16x16x32_bf16(
                    afrag[mi], bfrag[ni], acc[mi][ni], 0, 0, 0);
        __syncthreads();
    }

    // ---- epilogue: tanh(c + dec_proj) * v, reduce over a ----
    float decp[4], vv[4];
#pragma unroll
    for (int ni = 0; ni < 4; ++ni) {
        int a = wave * 64 + ni * 16 + l16;
        decp[ni] = dproj[b * ATTN + a];
        vv[ni]   = v[a];
    }
#pragma unroll
    for (int mi = 0; mi < 4; ++mi) {
#pragma unroll
        for (int r = 0; r < 4; ++r) {
            float sum = 0.0f;
#pragma unroll
            for (int ni = 0; ni < 4; ++ni) {
                float x = acc[mi][ni][r] + decp[ni];
                sum += fast_tanh(x) * vv[ni];
            }
            sum += __shfl_xor(sum, 1);
            sum += __shfl_xor(sum, 2);
            sum += __shfl_xor(sum, 4);
            sum += __shfl_xor(sum, 8);
            if (l16 == 0) {
                int m = mi * 16 + quad * 4 + r;
                sPart[m * 4 + wave] = sum;
            }
        }
    }
    __syncthreads();

    // ---- chunk-local softmax numerators (wave 0 only) ----
    if (tid < BM) {
        float s = sPart[tid * 4 + 0] + sPart[tid * 4 + 1] +
                  sPart[tid * 4 + 2] + sPart[tid * 4 + 3];
        scores[m0 + tid] = s;
        float m = s;
#pragma unroll
        for (int o = 1; o < 64; o <<= 1) m = fmaxf(m, __shfl_xor(m, o));
        float p = __expf(s - m);
        float l = p;
#pragma unroll
        for (int o = 1; o < 64; o <<= 1) l += __shfl_xor(l, o);
        sP[tid] = p;
        if (tid == 0) {
            ml[chunk * 2]     = m;
            ml[chunk * 2 + 1] = l;
        }
    }
    __syncthreads();

    // ---- pass 2: partial context from L2/L3-hot enc chunk (fp32) ----
    int e0 = tid * 2;
    const float* ebase = enc + (size_t)m0 * H_ENC + e0;
    float cx = 0.0f, cy = 0.0f;
#pragma unroll 4
    for (int t = 0; t < BM; ++t) {
        float wt = sP[t];
        float2 x = *(const float2*)(ebase + (size_t)t * H_ENC);
        cx += wt * x.x;
        cy += wt * x.y;
    }
    float* cp = ctxp + (size_t)chunk * H_ENC + e0;
    cp[0] = cx;
    cp[1] = cy;
}

// ---------------------------------------------------------------------------
// Kernel 3: combine — global softmax over chunks, write attn + context
// ---------------------------------------------------------------------------
__global__ __launch_bounds__(256) void combine_kernel(
    const float* __restrict__ scores,  // (B*T)
    const float* __restrict__ ctxp,    // (nchunks, 512)
    const float* __restrict__ ml,      // (nchunks, 2)
    float* __restrict__ out)           // ctx (B,512) then attn (B,4096)
{
    __shared__ float sc[64];
    __shared__ float sML[2];
    const int b = blockIdx.x;
    const int tid = threadIdx.x;
    const int nch = T_ENC / BM;  // 64 chunks per batch

    if (tid < nch) {
        float m = ml[(b * nch + tid) * 2];
        float l = ml[(b * nch + tid) * 2 + 1];
        float M = m;
#pragma unroll
        for (int o = 1; o < 64; o <<= 1) M = fmaxf(M, __shfl_xor(M, o));
        float scale = __expf(m - M);
        float contrib = l * scale;
        float L = contrib;
#pragma unroll
        for (int o = 1; o < 64; o <<= 1) L += __shfl_xor(L, o);
        sc[tid] = scale;
        if (tid == 0) { sML[0] = M; sML[1] = L; }
    }
    __syncthreads();
    const float M = sML[0];
    const float invL = 1.0f / sML[1];

    // attn weights: exact softmax from raw scores
    const float* sb = scores + (size_t)b * T_ENC;
    float* attn = out + B * H_ENC + (size_t)b * T_ENC;
#pragma unroll
    for (int i = 0; i < 16; ++i) {
        int t = i * 256 + tid;
        attn[t] = __expf(sb[t] - M) * invL;
    }

    // context: merge chunk partials
    int e0 = tid * 2;
    const float* cp = ctxp + ((size_t)b * nch) * H_ENC + e0;
    float cx = 0.0f, cy = 0.0f;
#pragma unroll 4
    for (int i = 0; i < nch; ++i) {
        float s = sc[i];
        float2 x = *(const float2*)(cp + (size_t)i * H_ENC);
        cx += s * x.x;
        cy += s * x.y;
    }
    out[b * H_ENC + e0]     = cx * invL;
    out[b * H_ENC + e0 + 1] = cy * invL;
}

extern "C" void kernel_launch(void* const* d_in, const int* in_sizes, int n_in,
                              void* d_out, int out_size, void* d_ws, size_t ws_size,
                              hipStream_t stream) {
    const float* dec  = (const float*)d_in[0];
    const float* enc  = (const float*)d_in[1];
    const float* Wenc = (const float*)d_in[2];
    const float* Wdec = (const float*)d_in[3];
    const float* v    = (const float*)d_in[4];
    float* out = (float*)d_out;
    float* ws  = (float*)d_ws;

    const int NCHUNK = (B * T_ENC) / BM;  // 4096

    float* scores = ws;                                  // 262144 floats
    float* dproj  = scores + (size_t)B * T_ENC;          // 16384 floats
    unsigned short* wencb = (unsigned short*)(dproj + B * ATTN);  // 131072 shorts
    float* ctxp = dproj + B * ATTN + (ATTN * H_ENC) / 2; // NCHUNK*512 floats
    float* ml   = ctxp + (size_t)NCHUNK * H_ENC;         // NCHUNK*2 floats

    hipLaunchKernelGGL(convw_kernel, dim3((ATTN * H_ENC) / 1024), dim3(256), 0, stream,
                       Wenc, wencb);
    hipLaunchKernelGGL(decproj_kernel, dim3(B), dim3(256), 0, stream, dec, Wdec, dproj);
    hipLaunchKernelGGL(fused_kernel, dim3(NCHUNK), dim3(256), 0, stream,
                       enc, wencb, dproj, v, scores, ctxp, ml);
    hipLaunchKernelGGL(combine_kernel, dim3(B), dim3(256), 0, stream,
                       scores, ctxp, ml, out);
}